// Round 1
// baseline (2106.368 us; speedup 1.0000x reference)
//
#include <hip/hip_runtime.h>

#define NN 50000
#define NE 800000
#define INC 128
#define HID 64
#define MH 128
#define EPSV 1e-5f
#define WS 132   // padded LDS row stride for 128-wide tiles

// ---------------- weight transpose (W1,W2 -> k-major) ----------------
__global__ void transpose_w_kernel(const float* __restrict__ W1, const float* __restrict__ W2,
                                   float* __restrict__ W1t, float* __restrict__ W2t) {
    int i = blockIdx.x * 256 + threadIdx.x;       // 0..32767
    if (i < 16384) {
        int oc = i >> 7, k = i & 127;
        W1t[k * 128 + oc] = W1[i];
    } else if (i < 32768) {
        int j = i - 16384;
        int oc = j >> 7, k = j & 127;
        W2t[k * 128 + oc] = W2[j];
    }
}

// ---------------- degree count ----------------
__global__ void cnt_kernel(const int* __restrict__ tgt, float* __restrict__ cnt) {
    int e = blockIdx.x * 256 + threadIdx.x;
    if (e < NE) atomicAdd(&cnt[tgt[e]], 1.0f);
}

// ---------------- layer 0 projections: xl = x@Wl.T ; pre = x@Wr.T + bl ; res = x@rW.T + rb ----------------
__global__ __launch_bounds__(256) void proj0_kernel(
    const float* __restrict__ x,
    const float* __restrict__ Wl, const float* __restrict__ bl,
    const float* __restrict__ Wr,
    const float* __restrict__ rW, const float* __restrict__ rb,
    float* __restrict__ xl, float* __restrict__ pre, float* __restrict__ res)
{
    __shared__ float swl[128 * 65];
    __shared__ float swr[128 * 65];
    __shared__ float swq[128 * 65];
    __shared__ float lx[4 * 128];
    __shared__ float lbl[64], lrb[64];
    const int tid = threadIdx.x;
    for (int i = tid; i < 64 * 128; i += 256) {
        int oc = i >> 7, k = i & 127;
        swl[k * 65 + oc] = Wl[i];
        swr[k * 65 + oc] = Wr[i];
        swq[k * 65 + oc] = rW[i];
    }
    if (tid < 64) { lbl[tid] = bl[tid]; lrb[tid] = rb[tid]; }
    __syncthreads();
    const int oc = tid & 63, nl = tid >> 6;
    for (int g = blockIdx.x; g < NN / 4; g += gridDim.x) {
        const int base = g * 4;
        for (int i = tid; i < 4 * 128; i += 256) lx[i] = x[base * 128 + i];
        __syncthreads();
        float a1 = 0.f, a2 = 0.f, a3 = 0.f;
        #pragma unroll 8
        for (int k = 0; k < 128; k++) {
            float xk = lx[nl * 128 + k];
            a1 = fmaf(xk, swl[k * 65 + oc], a1);
            a2 = fmaf(xk, swr[k * 65 + oc], a2);
            a3 = fmaf(xk, swq[k * 65 + oc], a3);
        }
        int node = base + nl;
        xl [node * 64 + oc] = a1;
        pre[node * 64 + oc] = a2 + lbl[oc];
        res[node * 64 + oc] = a3 + lrb[oc];
        __syncthreads();
    }
}

// ---------------- layers 1/2 projections ----------------
__global__ __launch_bounds__(256) void proj12_kernel(
    const float* __restrict__ h,
    const float* __restrict__ Wl, const float* __restrict__ bl,
    const float* __restrict__ Wr,
    float* __restrict__ xl, float* __restrict__ pre)
{
    __shared__ float swl[64 * 65];
    __shared__ float swr[64 * 65];
    __shared__ float lh[4 * 64];
    __shared__ float lbl[64];
    const int tid = threadIdx.x;
    for (int i = tid; i < 64 * 64; i += 256) {
        int oc = i >> 6, k = i & 63;
        swl[k * 65 + oc] = Wl[i];
        swr[k * 65 + oc] = Wr[i];
    }
    if (tid < 64) lbl[tid] = bl[tid];
    __syncthreads();
    const int oc = tid & 63, nl = tid >> 6;
    for (int g = blockIdx.x; g < NN / 4; g += gridDim.x) {
        const int base = g * 4;
        lh[tid] = h[base * 64 + tid];
        __syncthreads();
        float a1 = 0.f, a2 = 0.f;
        #pragma unroll 8
        for (int k = 0; k < 64; k++) {
            float hk = lh[nl * 64 + k];
            a1 = fmaf(hk, swl[k * 65 + oc], a1);
            a2 = fmaf(hk, swr[k * 65 + oc], a2);
        }
        int node = base + nl;
        xl [node * 64 + oc] = a1;
        pre[node * 64 + oc] = a2 + lbl[oc];
        __syncthreads();
    }
}

// ---------------- scatter-add of projected features ----------------
__global__ void scatter_kernel(const int* __restrict__ src, const int* __restrict__ tgt,
                               const float* __restrict__ xl, float* __restrict__ agg)
{
    const int stride = gridDim.x * 256;
    for (int idx = blockIdx.x * 256 + threadIdx.x; idx < NE * 64; idx += stride) {
        int e = idx >> 6, c = idx & 63;
        atomicAdd(&agg[tgt[e] * 64 + c], xl[src[e] * 64 + c]);
    }
}

// ---------------- mean + self term, BN statistics ----------------
__global__ __launch_bounds__(256) void combine_kernel(
    const float* __restrict__ cnt, const float* __restrict__ pre,
    float* agg /* in-out: becomes pre-BN activations */,
    float* __restrict__ bnsum, float* __restrict__ bnsq)
{
    __shared__ float r1[256], r2[256];
    const int tid = threadIdx.x;
    const int c = tid & 63, nl = tid >> 6;
    float s = 0.f, q = 0.f;
    for (int g = blockIdx.x; g < NN / 4; g += gridDim.x) {
        int i = g * 4 + nl;
        float ct = cnt[i];
        float v = agg[i * 64 + c] / fmaxf(ct, 1.0f) + pre[i * 64 + c];
        agg[i * 64 + c] = v;
        s += v; q += v * v;
    }
    r1[tid] = s; r2[tid] = q;
    __syncthreads();
    if (tid < 64) {
        s = r1[tid] + r1[tid + 64] + r1[tid + 128] + r1[tid + 192];
        q = r2[tid] + r2[tid + 64] + r2[tid + 128] + r2[tid + 192];
        atomicAdd(&bnsum[tid], s);
        atomicAdd(&bnsq[tid], q);
    }
}

// ---------------- BN finalize ----------------
__global__ void bnfin_kernel(const float* __restrict__ bnsum, const float* __restrict__ bnsq,
                             const float* __restrict__ g, const float* __restrict__ be,
                             float* __restrict__ scale, float* __restrict__ shift)
{
    int c = threadIdx.x;  // 64
    float inv_n = 1.0f / (float)NN;
    float mu = bnsum[c] * inv_n;
    float var = bnsq[c] * inv_n - mu * mu;
    float rstd = rsqrtf(var + EPSV);
    float sc = g[c] * rstd;
    scale[c] = sc;
    shift[c] = be[c] - mu * sc;
}

// ---------------- BN apply + ReLU + residual ----------------
__global__ void apply_kernel(const float* __restrict__ outp, const float* res,
                             const float* __restrict__ scale, const float* __restrict__ shift,
                             float* h)
{
    const int stride = gridDim.x * 256;
    for (int i = blockIdx.x * 256 + threadIdx.x; i < NN * 16; i += stride) {
        int c0 = (i & 15) * 4;
        float4 v = *(const float4*)&outp[i * 4];
        float4 r = *(const float4*)&res[i * 4];
        float4 o;
        o.x = fmaxf(fmaf(v.x, scale[c0 + 0], shift[c0 + 0]), 0.f) + r.x;
        o.y = fmaxf(fmaf(v.y, scale[c0 + 1], shift[c0 + 1]), 0.f) + r.y;
        o.z = fmaxf(fmaf(v.z, scale[c0 + 2], shift[c0 + 2]), 0.f) + r.z;
        o.w = fmaxf(fmaf(v.w, scale[c0 + 3], shift[c0 + 3]), 0.f) + r.w;
        *(float4*)&h[i * 4] = o;
    }
}

// ---------------- fused edge MLP ----------------
__device__ __forceinline__ void mlp128(const float* srcb, float* dstb,
                                       const float* Wt, const float* bb, int tid)
{
    const int oc0 = (tid & 15) * 8;
    const int eb  = (tid >> 4) * 4;
    float acc[4][8];
    #pragma unroll
    for (int m = 0; m < 4; m++)
        #pragma unroll
        for (int n = 0; n < 8; n++) acc[m][n] = bb[oc0 + n];
    for (int k = 0; k < 128; k += 4) {
        float a[4][4];
        #pragma unroll
        for (int m = 0; m < 4; m++)
            *(float4*)&a[m][0] = *(const float4*)&srcb[(eb + m) * WS + k];
        #pragma unroll
        for (int kk = 0; kk < 4; kk++) {
            const float4 w0 = *(const float4*)&Wt[(k + kk) * WS + oc0];
            const float4 w1 = *(const float4*)&Wt[(k + kk) * WS + oc0 + 4];
            #pragma unroll
            for (int m = 0; m < 4; m++) {
                const float av = a[m][kk];
                acc[m][0] = fmaf(av, w0.x, acc[m][0]);
                acc[m][1] = fmaf(av, w0.y, acc[m][1]);
                acc[m][2] = fmaf(av, w0.z, acc[m][2]);
                acc[m][3] = fmaf(av, w0.w, acc[m][3]);
                acc[m][4] = fmaf(av, w1.x, acc[m][4]);
                acc[m][5] = fmaf(av, w1.y, acc[m][5]);
                acc[m][6] = fmaf(av, w1.z, acc[m][6]);
                acc[m][7] = fmaf(av, w1.w, acc[m][7]);
            }
        }
    }
    #pragma unroll
    for (int m = 0; m < 4; m++) {
        float4 o0 = make_float4(fmaxf(acc[m][0], 0.f), fmaxf(acc[m][1], 0.f),
                                fmaxf(acc[m][2], 0.f), fmaxf(acc[m][3], 0.f));
        float4 o1 = make_float4(fmaxf(acc[m][4], 0.f), fmaxf(acc[m][5], 0.f),
                                fmaxf(acc[m][6], 0.f), fmaxf(acc[m][7], 0.f));
        *(float4*)&dstb[(eb + m) * WS + oc0]     = o0;
        *(float4*)&dstb[(eb + m) * WS + oc0 + 4] = o1;
    }
}

__global__ __launch_bounds__(256) void edge_mlp_kernel(
    const float* __restrict__ h,
    const int* __restrict__ src, const int* __restrict__ tgt,
    const float* __restrict__ W1t, const float* __restrict__ b1,
    const float* __restrict__ W2t, const float* __restrict__ b2,
    const float* __restrict__ W3, const float* __restrict__ b3,
    float* __restrict__ out)
{
    __shared__ float Wt[128 * WS];
    __shared__ float inb[64 * WS];
    __shared__ float zb[64 * WS];
    __shared__ float bb[128];
    __shared__ float w3s[128];
    __shared__ float red[256];
    __shared__ int se[64], te[64];
    const int tid = threadIdx.x;
    const int e0 = blockIdx.x * 64;
    if (tid < 64) { se[tid] = src[e0 + tid]; te[tid] = tgt[e0 + tid]; }
    if (tid < 128) w3s[tid] = W3[tid];
    __syncthreads();
    // stage edge inputs: concat(h[src], h[tgt])
    for (int i = tid; i < 64 * 32; i += 256) {
        int e = i >> 5;
        int c0 = (i & 31) * 4;
        int node = (c0 < 64) ? se[e] : te[e];
        float4 v = *(const float4*)&h[node * 64 + (c0 & 63)];
        *(float4*)&inb[e * WS + c0] = v;
    }
    // stage W1t + b1
    for (int i = tid; i < 128 * 32; i += 256) {
        int k = i >> 5, c0 = (i & 31) * 4;
        *(float4*)&Wt[k * WS + c0] = *(const float4*)&W1t[k * 128 + c0];
    }
    if (tid < 128) bb[tid] = b1[tid];
    __syncthreads();
    mlp128(inb, zb, Wt, bb, tid);     // z1 = relu(in @ W1.T + b1)
    __syncthreads();
    // stage W2t + b2
    for (int i = tid; i < 128 * 32; i += 256) {
        int k = i >> 5, c0 = (i & 31) * 4;
        *(float4*)&Wt[k * WS + c0] = *(const float4*)&W2t[k * 128 + c0];
    }
    if (tid < 128) bb[tid] = b2[tid];
    __syncthreads();
    mlp128(zb, inb, Wt, bb, tid);     // z2 = relu(z1 @ W2.T + b2)
    __syncthreads();
    // z3 = z2 @ W3.T + b3
    const int e = tid & 63, kq = tid >> 6;
    float p = 0.f;
    #pragma unroll 8
    for (int k = kq * 32; k < kq * 32 + 32; k++) p = fmaf(inb[e * WS + k], w3s[k], p);
    red[tid] = p;
    __syncthreads();
    if (tid < 64)
        out[e0 + tid] = red[tid] + red[tid + 64] + red[tid + 128] + red[tid + 192] + b3[0];
}

// ---------------- launch ----------------
extern "C" void kernel_launch(void* const* d_in, const int* in_sizes, int n_in,
                              void* d_out, int out_size, void* d_ws, size_t ws_size,
                              hipStream_t stream)
{
    const float* x   = (const float*)d_in[0];
    const int*   ei  = (const int*)d_in[1];
    const int* src = ei;
    const int* tgt = ei + NE;
    const float* Wl0 = (const float*)d_in[2];
    const float* bl0 = (const float*)d_in[3];
    const float* Wr0 = (const float*)d_in[4];
    const float* g0  = (const float*)d_in[5];
    const float* be0 = (const float*)d_in[6];
    const float* rW0 = (const float*)d_in[7];
    const float* rb0 = (const float*)d_in[8];
    const float* Wl1 = (const float*)d_in[9];
    const float* bl1 = (const float*)d_in[10];
    const float* Wr1 = (const float*)d_in[11];
    const float* g1  = (const float*)d_in[12];
    const float* be1 = (const float*)d_in[13];
    const float* Wl2 = (const float*)d_in[14];
    const float* bl2 = (const float*)d_in[15];
    const float* Wr2 = (const float*)d_in[16];
    const float* g2  = (const float*)d_in[17];
    const float* be2 = (const float*)d_in[18];
    const float* W1  = (const float*)d_in[19];
    const float* b1  = (const float*)d_in[20];
    const float* W2  = (const float*)d_in[21];
    const float* b2  = (const float*)d_in[22];
    const float* W3  = (const float*)d_in[23];
    const float* b3  = (const float*)d_in[24];
    float* out = (float*)d_out;

    float* ws = (float*)d_ws;
    const long long NH = (long long)NN * HID;   // 3,200,000
    float* xl    = ws;
    float* pre   = ws +     NH;
    float* res   = ws + 2 * NH;
    float* agg   = ws + 3 * NH;
    float* bnsum = ws + 4 * NH;          // 64
    float* bnsq  = bnsum + 64;           // 64
    float* bnsc  = bnsum + 128;          // 64
    float* bnsh  = bnsum + 192;          // 64
    float* cnt   = bnsum + 256;          // NN
    float* hbuf  = cnt + NN;             // NH
    float* W1t   = hbuf + NH;            // 16384
    float* W2t   = W1t + 16384;          // 16384

    hipMemsetAsync(cnt, 0, NN * sizeof(float), stream);
    transpose_w_kernel<<<128, 256, 0, stream>>>(W1, W2, W1t, W2t);
    cnt_kernel<<<NE / 256, 256, 0, stream>>>(tgt, cnt);

    // ---- layer 0 ----
    hipMemsetAsync(agg, 0, (NH + 128) * sizeof(float), stream);
    proj0_kernel<<<2048, 256, 0, stream>>>(x, Wl0, bl0, Wr0, rW0, rb0, xl, pre, res);
    scatter_kernel<<<4096, 256, 0, stream>>>(src, tgt, xl, agg);
    combine_kernel<<<256, 256, 0, stream>>>(cnt, pre, agg, bnsum, bnsq);
    bnfin_kernel<<<1, 64, 0, stream>>>(bnsum, bnsq, g0, be0, bnsc, bnsh);
    apply_kernel<<<1024, 256, 0, stream>>>(agg, res, bnsc, bnsh, hbuf);

    // ---- layer 1 ----
    hipMemsetAsync(agg, 0, (NH + 128) * sizeof(float), stream);
    proj12_kernel<<<2048, 256, 0, stream>>>(hbuf, Wl1, bl1, Wr1, xl, pre);
    scatter_kernel<<<4096, 256, 0, stream>>>(src, tgt, xl, agg);
    combine_kernel<<<256, 256, 0, stream>>>(cnt, pre, agg, bnsum, bnsq);
    bnfin_kernel<<<1, 64, 0, stream>>>(bnsum, bnsq, g1, be1, bnsc, bnsh);
    apply_kernel<<<1024, 256, 0, stream>>>(agg, hbuf, bnsc, bnsh, hbuf);

    // ---- layer 2 ----
    hipMemsetAsync(agg, 0, (NH + 128) * sizeof(float), stream);
    proj12_kernel<<<2048, 256, 0, stream>>>(hbuf, Wl2, bl2, Wr2, xl, pre);
    scatter_kernel<<<4096, 256, 0, stream>>>(src, tgt, xl, agg);
    combine_kernel<<<256, 256, 0, stream>>>(cnt, pre, agg, bnsum, bnsq);
    bnfin_kernel<<<1, 64, 0, stream>>>(bnsum, bnsq, g2, be2, bnsc, bnsh);
    apply_kernel<<<1024, 256, 0, stream>>>(agg, hbuf, bnsc, bnsh, hbuf);

    // ---- edge MLP ----
    edge_mlp_kernel<<<NE / 64, 256, 0, stream>>>(hbuf, src, tgt, W1t, b1, W2t, b2, W3, b3, out);
}

// Round 2
// 1119.920 us; speedup vs baseline: 1.8808x; 1.8808x over previous
//
#include <hip/hip_runtime.h>
#include <hip/hip_bf16.h>

#define NN 50000
#define NE 800000
#define HID 64
#define EPSV 1e-5f

typedef __attribute__((ext_vector_type(8))) short bf16x8;
typedef __attribute__((ext_vector_type(4))) float f32x4;
typedef __attribute__((ext_vector_type(4))) int int4v;

__device__ __forceinline__ ushort f2b(float f) {
    union { __hip_bfloat16 b; ushort u; } c;
    c.b = __float2bfloat16(f);
    return c.u;
}

// ---------------- weight f32 -> bf16 prep ----------------
__global__ void prep_w_kernel(const float* __restrict__ W1, const float* __restrict__ W2,
                              ushort* __restrict__ W1b, ushort* __restrict__ W2b) {
    int i = blockIdx.x * 256 + threadIdx.x;   // 0..32767
    if (i < 16384) W1b[i] = f2b(W1[i]);
    else           W2b[i - 16384] = f2b(W2[i - 16384]);
}

// ---------------- degree count ----------------
__global__ void cnt_kernel(const int* __restrict__ tgt, float* __restrict__ cnt) {
    int e = blockIdx.x * 256 + threadIdx.x;
    if (e < NE) atomicAdd(&cnt[tgt[e]], 1.0f);
}

// ---------------- layer 0 projections ----------------
__global__ __launch_bounds__(256) void proj0_kernel(
    const float* __restrict__ x,
    const float* __restrict__ Wl, const float* __restrict__ bl,
    const float* __restrict__ Wr,
    const float* __restrict__ rW, const float* __restrict__ rb,
    float* __restrict__ xl, float* __restrict__ pre, float* __restrict__ res)
{
    __shared__ float swl[128 * 65];
    __shared__ float swr[128 * 65];
    __shared__ float swq[128 * 65];
    __shared__ float lx[4 * 128];
    __shared__ float lbl[64], lrb[64];
    const int tid = threadIdx.x;
    for (int i = tid; i < 64 * 128; i += 256) {
        int oc = i >> 7, k = i & 127;
        swl[k * 65 + oc] = Wl[i];
        swr[k * 65 + oc] = Wr[i];
        swq[k * 65 + oc] = rW[i];
    }
    if (tid < 64) { lbl[tid] = bl[tid]; lrb[tid] = rb[tid]; }
    __syncthreads();
    const int oc = tid & 63, nl = tid >> 6;
    for (int g = blockIdx.x; g < NN / 4; g += gridDim.x) {
        const int base = g * 4;
        for (int i = tid; i < 4 * 128; i += 256) lx[i] = x[base * 128 + i];
        __syncthreads();
        float a1 = 0.f, a2 = 0.f, a3 = 0.f;
        #pragma unroll 8
        for (int k = 0; k < 128; k++) {
            float xk = lx[nl * 128 + k];
            a1 = fmaf(xk, swl[k * 65 + oc], a1);
            a2 = fmaf(xk, swr[k * 65 + oc], a2);
            a3 = fmaf(xk, swq[k * 65 + oc], a3);
        }
        int node = base + nl;
        xl [node * 64 + oc] = a1;
        pre[node * 64 + oc] = a2 + lbl[oc];
        res[node * 64 + oc] = a3 + lrb[oc];
        __syncthreads();
    }
}

// ---------------- layers 1/2 projections ----------------
__global__ __launch_bounds__(256) void proj12_kernel(
    const float* __restrict__ h,
    const float* __restrict__ Wl, const float* __restrict__ bl,
    const float* __restrict__ Wr,
    float* __restrict__ xl, float* __restrict__ pre)
{
    __shared__ float swl[64 * 65];
    __shared__ float swr[64 * 65];
    __shared__ float lh[4 * 64];
    __shared__ float lbl[64];
    const int tid = threadIdx.x;
    for (int i = tid; i < 64 * 64; i += 256) {
        int oc = i >> 6, k = i & 63;
        swl[k * 65 + oc] = Wl[i];
        swr[k * 65 + oc] = Wr[i];
    }
    if (tid < 64) lbl[tid] = bl[tid];
    __syncthreads();
    const int oc = tid & 63, nl = tid >> 6;
    for (int g = blockIdx.x; g < NN / 4; g += gridDim.x) {
        const int base = g * 4;
        lh[tid] = h[base * 64 + tid];
        __syncthreads();
        float a1 = 0.f, a2 = 0.f;
        #pragma unroll 8
        for (int k = 0; k < 64; k++) {
            float hk = lh[nl * 64 + k];
            a1 = fmaf(hk, swl[k * 65 + oc], a1);
            a2 = fmaf(hk, swr[k * 65 + oc], a2);
        }
        int node = base + nl;
        xl [node * 64 + oc] = a1;
        pre[node * 64 + oc] = a2 + lbl[oc];
        __syncthreads();
    }
}

// ---------------- scatter-add of projected features ----------------
__global__ void scatter_kernel(const int* __restrict__ src, const int* __restrict__ tgt,
                               const float* __restrict__ xl, float* __restrict__ agg)
{
    const int stride = gridDim.x * 256;
    for (int idx = blockIdx.x * 256 + threadIdx.x; idx < NE * 64; idx += stride) {
        int e = idx >> 6, c = idx & 63;
        atomicAdd(&agg[tgt[e] * 64 + c], xl[src[e] * 64 + c]);
    }
}

// ---------------- mean + self term, BN statistics ----------------
__global__ __launch_bounds__(256) void combine_kernel(
    const float* __restrict__ cnt, const float* __restrict__ pre,
    float* agg, float* __restrict__ bnsum, float* __restrict__ bnsq)
{
    __shared__ float r1[256], r2[256];
    const int tid = threadIdx.x;
    const int c = tid & 63, nl = tid >> 6;
    float s = 0.f, q = 0.f;
    for (int g = blockIdx.x; g < NN / 4; g += gridDim.x) {
        int i = g * 4 + nl;
        float ct = cnt[i];
        float v = agg[i * 64 + c] / fmaxf(ct, 1.0f) + pre[i * 64 + c];
        agg[i * 64 + c] = v;
        s += v; q += v * v;
    }
    r1[tid] = s; r2[tid] = q;
    __syncthreads();
    if (tid < 64) {
        s = r1[tid] + r1[tid + 64] + r1[tid + 128] + r1[tid + 192];
        q = r2[tid] + r2[tid + 64] + r2[tid + 128] + r2[tid + 192];
        atomicAdd(&bnsum[tid], s);
        atomicAdd(&bnsq[tid], q);
    }
}

// ---------------- BN finalize ----------------
__global__ void bnfin_kernel(const float* __restrict__ bnsum, const float* __restrict__ bnsq,
                             const float* __restrict__ g, const float* __restrict__ be,
                             float* __restrict__ scale, float* __restrict__ shift)
{
    int c = threadIdx.x;  // 64
    float inv_n = 1.0f / (float)NN;
    float mu = bnsum[c] * inv_n;
    float var = bnsq[c] * inv_n - mu * mu;
    float rstd = rsqrtf(var + EPSV);
    float sc = g[c] * rstd;
    scale[c] = sc;
    shift[c] = be[c] - mu * sc;
}

// ---------------- BN apply + ReLU + residual (f32 + bf16 outputs) ----------------
__global__ void apply_kernel(const float* __restrict__ outp, const float* res,
                             const float* __restrict__ scale, const float* __restrict__ shift,
                             float* h, ushort* hb)
{
    const int stride = gridDim.x * 256;
    for (int i = blockIdx.x * 256 + threadIdx.x; i < NN * 16; i += stride) {
        int c0 = (i & 15) * 4;
        float4 v = *(const float4*)&outp[i * 4];
        float4 r = *(const float4*)&res[i * 4];
        float4 o;
        o.x = fmaxf(fmaf(v.x, scale[c0 + 0], shift[c0 + 0]), 0.f) + r.x;
        o.y = fmaxf(fmaf(v.y, scale[c0 + 1], shift[c0 + 1]), 0.f) + r.y;
        o.z = fmaxf(fmaf(v.z, scale[c0 + 2], shift[c0 + 2]), 0.f) + r.z;
        o.w = fmaxf(fmaf(v.w, scale[c0 + 3], shift[c0 + 3]), 0.f) + r.w;
        *(float4*)&h[i * 4] = o;
        union { ushort u[4]; uint2 v2; } p;
        p.u[0] = f2b(o.x); p.u[1] = f2b(o.y); p.u[2] = f2b(o.z); p.u[3] = f2b(o.w);
        *(uint2*)&hb[i * 4] = p.v2;
    }
}

// ---------------- fused edge MLP, bf16 MFMA ----------------
// 512 threads = 8 waves: esplit = wid&3 (32 edges each), osplit = wid>>2 (64 ocs each).
// Weights held in VGPR frags, loaded once per block; grid-stride over 128-edge tiles.
#define TILE 128
#define PADB 136   // bf16 units; rows 16B-aligned; A-frag reads bank-uniform

__global__ __launch_bounds__(512, 2) void edge_mlp_mfma_kernel(
    const ushort* __restrict__ hb,
    const int* __restrict__ src, const int* __restrict__ tgt,
    const ushort* __restrict__ W1b, const ushort* __restrict__ W2b,
    const float* __restrict__ b1, const float* __restrict__ b2,
    const float* __restrict__ W3, const float* __restrict__ b3,
    float* __restrict__ out)
{
    __shared__ ushort inb[TILE * PADB];
    __shared__ ushort zb [TILE * PADB];
    __shared__ float red[2][TILE];

    const int tid = threadIdx.x;
    const int wid = tid >> 6, lane = tid & 63;
    const int l15 = lane & 15, l4 = lane >> 4;
    const int es = wid & 3, os = wid >> 2;
    const int m0 = es * 32;
    const int ocb = os * 64;

    // persistent weight fragments: B[k][oc] = W[oc][k], lane holds oc=l15, k=ks*32+l4*8+j
    bf16x8 w1f[4][4], w2f[4][4];
    #pragma unroll
    for (int n = 0; n < 4; n++) {
        const int oc = ocb + n * 16 + l15;
        #pragma unroll
        for (int ks = 0; ks < 4; ks++) {
            const int k = ks * 32 + l4 * 8;
            w1f[n][ks] = *(const bf16x8*)&W1b[oc * 128 + k];
            w2f[n][ks] = *(const bf16x8*)&W2b[oc * 128 + k];
        }
    }
    float b1v[4], b2v[4], w3v[4];
    #pragma unroll
    for (int n = 0; n < 4; n++) {
        b1v[n] = b1[ocb + n * 16 + l15];
        b2v[n] = b2[ocb + n * 16 + l15];
        w3v[n] = W3[ocb + n * 16 + l15];
    }
    const float b3v = b3[0];

    for (int t = blockIdx.x; t < NE / TILE; t += gridDim.x) {
        const int e0 = t * TILE;
        // ---- stage concat(hb[src], hb[tgt]) -> inb (bf16) ----
        for (int i = tid; i < TILE * 16; i += 512) {
            int e = i >> 4, q = i & 15;
            int node = (q < 8) ? src[e0 + e] : tgt[e0 + e];
            int c8 = (q & 7) * 8;
            int4v v = *(const int4v*)&hb[node * 64 + c8];
            *(int4v*)&inb[e * PADB + ((q & 8) << 3) + c8] = v;
        }
        __syncthreads();

        // ---- layer 1: Z1 = relu(IN @ W1.T + b1) ----
        f32x4 acc1[2][4];
        #pragma unroll
        for (int ms = 0; ms < 2; ms++)
            #pragma unroll
            for (int n = 0; n < 4; n++)
                acc1[ms][n] = (f32x4){b1v[n], b1v[n], b1v[n], b1v[n]};
        #pragma unroll
        for (int ms = 0; ms < 2; ms++) {
            const int erow = m0 + ms * 16 + l15;
            #pragma unroll
            for (int ks = 0; ks < 4; ks++) {
                bf16x8 a = *(const bf16x8*)&inb[erow * PADB + ks * 32 + l4 * 8];
                #pragma unroll
                for (int n = 0; n < 4; n++)
                    acc1[ms][n] = __builtin_amdgcn_mfma_f32_16x16x32_bf16(a, w1f[n][ks], acc1[ms][n], 0, 0, 0);
            }
        }
        #pragma unroll
        for (int ms = 0; ms < 2; ms++)
            #pragma unroll
            for (int n = 0; n < 4; n++) {
                const int ebase = m0 + ms * 16 + l4 * 4;
                const int oc = ocb + n * 16 + l15;
                #pragma unroll
                for (int r = 0; r < 4; r++)
                    zb[(ebase + r) * PADB + oc] = f2b(fmaxf(acc1[ms][n][r], 0.f));
            }
        __syncthreads();

        // ---- layer 2: Z2 = relu(Z1 @ W2.T + b2), kept in regs ----
        f32x4 acc2[2][4];
        #pragma unroll
        for (int ms = 0; ms < 2; ms++)
            #pragma unroll
            for (int n = 0; n < 4; n++)
                acc2[ms][n] = (f32x4){b2v[n], b2v[n], b2v[n], b2v[n]};
        #pragma unroll
        for (int ms = 0; ms < 2; ms++) {
            const int erow = m0 + ms * 16 + l15;
            #pragma unroll
            for (int ks = 0; ks < 4; ks++) {
                bf16x8 a = *(const bf16x8*)&zb[erow * PADB + ks * 32 + l4 * 8];
                #pragma unroll
                for (int n = 0; n < 4; n++)
                    acc2[ms][n] = __builtin_amdgcn_mfma_f32_16x16x32_bf16(a, w2f[n][ks], acc2[ms][n], 0, 0, 0);
            }
        }

        // ---- layer 3: out = relu(Z2) @ W3.T + b3 (f32, in-register) ----
        #pragma unroll
        for (int ms = 0; ms < 2; ms++) {
            #pragma unroll
            for (int r = 0; r < 4; r++) {
                float p = 0.f;
                #pragma unroll
                for (int n = 0; n < 4; n++)
                    p = fmaf(fmaxf(acc2[ms][n][r], 0.f), w3v[n], p);
                p += __shfl_xor(p, 1);
                p += __shfl_xor(p, 2);
                p += __shfl_xor(p, 4);
                p += __shfl_xor(p, 8);
                if (l15 == 0) red[os][m0 + ms * 16 + l4 * 4 + r] = p;
            }
        }
        __syncthreads();
        if (tid < TILE) out[e0 + tid] = red[0][tid] + red[1][tid] + b3v;
        __syncthreads();
    }
}

// ---------------- launch ----------------
extern "C" void kernel_launch(void* const* d_in, const int* in_sizes, int n_in,
                              void* d_out, int out_size, void* d_ws, size_t ws_size,
                              hipStream_t stream)
{
    const float* x   = (const float*)d_in[0];
    const int*   ei  = (const int*)d_in[1];
    const int* src = ei;
    const int* tgt = ei + NE;
    const float* Wl0 = (const float*)d_in[2];
    const float* bl0 = (const float*)d_in[3];
    const float* Wr0 = (const float*)d_in[4];
    const float* g0  = (const float*)d_in[5];
    const float* be0 = (const float*)d_in[6];
    const float* rW0 = (const float*)d_in[7];
    const float* rb0 = (const float*)d_in[8];
    const float* Wl1 = (const float*)d_in[9];
    const float* bl1 = (const float*)d_in[10];
    const float* Wr1 = (const float*)d_in[11];
    const float* g1  = (const float*)d_in[12];
    const float* be1 = (const float*)d_in[13];
    const float* Wl2 = (const float*)d_in[14];
    const float* bl2 = (const float*)d_in[15];
    const float* Wr2 = (const float*)d_in[16];
    const float* g2  = (const float*)d_in[17];
    const float* be2 = (const float*)d_in[18];
    const float* W1  = (const float*)d_in[19];
    const float* b1  = (const float*)d_in[20];
    const float* W2  = (const float*)d_in[21];
    const float* b2  = (const float*)d_in[22];
    const float* W3  = (const float*)d_in[23];
    const float* b3  = (const float*)d_in[24];
    float* out = (float*)d_out;

    float* ws = (float*)d_ws;
    const long long NH = (long long)NN * HID;   // 3,200,000
    float* xl    = ws;
    float* pre   = ws +     NH;
    float* res   = ws + 2 * NH;
    float* agg   = ws + 3 * NH;
    float* bnsum = ws + 4 * NH;          // 64
    float* bnsq  = bnsum + 64;           // 64
    float* bnsc  = bnsum + 128;          // 64
    float* bnsh  = bnsum + 192;          // 64
    float* cnt   = bnsum + 256;          // NN
    float* hbuf  = cnt + NN;             // NH
    ushort* W1b  = (ushort*)(hbuf + NH); // 16384 ushort
    ushort* W2b  = W1b + 16384;          // 16384 ushort
    ushort* hb_junk = (ushort*)xl;       // scratch target for layers 0/1 (xl rewritten by next proj)
    ushort* hb_real = (ushort*)res;      // res dead after layer 0

    hipMemsetAsync(cnt, 0, NN * sizeof(float), stream);
    prep_w_kernel<<<128, 256, 0, stream>>>(W1, W2, W1b, W2b);
    cnt_kernel<<<NE / 256, 256, 0, stream>>>(tgt, cnt);

    // ---- layer 0 ----
    hipMemsetAsync(agg, 0, (NH + 128) * sizeof(float), stream);
    proj0_kernel<<<2048, 256, 0, stream>>>(x, Wl0, bl0, Wr0, rW0, rb0, xl, pre, res);
    scatter_kernel<<<4096, 256, 0, stream>>>(src, tgt, xl, agg);
    combine_kernel<<<256, 256, 0, stream>>>(cnt, pre, agg, bnsum, bnsq);
    bnfin_kernel<<<1, 64, 0, stream>>>(bnsum, bnsq, g0, be0, bnsc, bnsh);
    apply_kernel<<<1024, 256, 0, stream>>>(agg, res, bnsc, bnsh, hbuf, hb_junk);

    // ---- layer 1 ----
    hipMemsetAsync(agg, 0, (NH + 128) * sizeof(float), stream);
    proj12_kernel<<<2048, 256, 0, stream>>>(hbuf, Wl1, bl1, Wr1, xl, pre);
    scatter_kernel<<<4096, 256, 0, stream>>>(src, tgt, xl, agg);
    combine_kernel<<<256, 256, 0, stream>>>(cnt, pre, agg, bnsum, bnsq);
    bnfin_kernel<<<1, 64, 0, stream>>>(bnsum, bnsq, g1, be1, bnsc, bnsh);
    apply_kernel<<<1024, 256, 0, stream>>>(agg, hbuf, bnsc, bnsh, hbuf, hb_junk);

    // ---- layer 2 ----
    hipMemsetAsync(agg, 0, (NH + 128) * sizeof(float), stream);
    proj12_kernel<<<2048, 256, 0, stream>>>(hbuf, Wl2, bl2, Wr2, xl, pre);
    scatter_kernel<<<4096, 256, 0, stream>>>(src, tgt, xl, agg);
    combine_kernel<<<256, 256, 0, stream>>>(cnt, pre, agg, bnsum, bnsq);
    bnfin_kernel<<<1, 64, 0, stream>>>(bnsum, bnsq, g2, be2, bnsc, bnsh);
    apply_kernel<<<1024, 256, 0, stream>>>(agg, hbuf, bnsc, bnsh, hbuf, hb_real);

    // ---- edge MLP (bf16 MFMA) ----
    edge_mlp_mfma_kernel<<<625, 512, 0, stream>>>(hb_real, src, tgt, W1b, W2b, b1, b2, W3, b3, out);
}

// Round 3
// 806.455 us; speedup vs baseline: 2.6119x; 1.3887x over previous
//
#include <hip/hip_runtime.h>
#include <hip/hip_bf16.h>

#define NN 50000
#define NE 800000
#define HID 64
#define EPSV 1e-5f
#define NBLK 196            // ceil(NN/256)

typedef __attribute__((ext_vector_type(8))) short bf16x8;
typedef __attribute__((ext_vector_type(4))) float f32x4;
typedef __attribute__((ext_vector_type(4))) int int4v;

__device__ __forceinline__ ushort f2b(float f) {
    union { __hip_bfloat16 b; ushort u; } c;
    c.b = __float2bfloat16(f);
    return c.u;
}

// ---------------- weight f32 -> bf16 prep (edge MLP) ----------------
__global__ void prep_w_kernel(const float* __restrict__ W1, const float* __restrict__ W2,
                              ushort* __restrict__ W1b, ushort* __restrict__ W2b) {
    int i = blockIdx.x * 256 + threadIdx.x;   // 0..32767
    if (i < 16384) W1b[i] = f2b(W1[i]);
    else           W2b[i - 16384] = f2b(W2[i - 16384]);
}

// ---------------- CSR build: count, scan, fill ----------------
__global__ void count_kernel(const int* __restrict__ tgt, int* __restrict__ icnt) {
    int e = blockIdx.x * 256 + threadIdx.x;
    if (e < NE) atomicAdd(&icnt[tgt[e]], 1);
}

__global__ void scan1_kernel(const int* __restrict__ icnt, int* __restrict__ off,
                             int* __restrict__ bsum) {
    __shared__ int s[256];
    const int t = threadIdx.x;
    const int i = blockIdx.x * 256 + t;
    int v = (i < NN) ? icnt[i] : 0;
    s[t] = v;
    __syncthreads();
    for (int d = 1; d < 256; d <<= 1) {
        int x = (t >= d) ? s[t - d] : 0;
        __syncthreads();
        s[t] += x;
        __syncthreads();
    }
    if (i < NN) off[i] = s[t];             // inclusive, block-local
    if (t == 255) bsum[blockIdx.x] = s[255];
}

__global__ void scan2_kernel(const int* __restrict__ bsum, int* __restrict__ bpre) {
    __shared__ int s[256];
    const int t = threadIdx.x;
    int v = (t < NBLK) ? bsum[t] : 0;
    s[t] = v;
    __syncthreads();
    for (int d = 1; d < 256; d <<= 1) {
        int x = (t >= d) ? s[t - d] : 0;
        __syncthreads();
        s[t] += x;
        __syncthreads();
    }
    if (t < NBLK) bpre[t] = s[t] - v;      // exclusive
}

__global__ void scan3_kernel(const int* __restrict__ icnt, const int* __restrict__ bpre,
                             int* __restrict__ off, int* __restrict__ woff) {
    const int i = blockIdx.x * 256 + threadIdx.x;
    if (i < NN) {
        int e = off[i] - icnt[i] + bpre[blockIdx.x];   // exclusive global
        off[i] = e;
        woff[i] = e;
        if (i == NN - 1) off[NN] = NE;
    }
}

__global__ void fill_kernel(const int* __restrict__ src, const int* __restrict__ tgt,
                            int* __restrict__ woff, int* __restrict__ ebuf) {
    int e = blockIdx.x * 256 + threadIdx.x;
    if (e < NE) {
        int p = atomicAdd(&woff[tgt[e]], 1);
        ebuf[p] = src[e];
    }
}

// ---------------- projection GEMM: C[n][seg*64+oc] = A[n][:] @ W_seg[oc][:] + b_seg ----------------
// BM=256 nodes x BN=64 oc per block, 256 threads, 8x8 micro-tile, BK=32.
#define PADA 260
#define PADBW 68

__global__ __launch_bounds__(256, 2) void proj_gemm_kernel(
    const float* __restrict__ A, int K,
    const float* __restrict__ W0, const float* __restrict__ W1s,
    const float* __restrict__ W2s,
    const float* __restrict__ bb0, const float* __restrict__ bb1,
    const float* __restrict__ bb2,
    float* __restrict__ C, int Ntot)
{
    __shared__ float At[32 * PADA];
    __shared__ float Bt[32 * PADBW];
    const int tid = threadIdx.x;
    const int seg = blockIdx.y;
    const float* W  = (seg == 0) ? W0 : ((seg == 1) ? W1s : W2s);
    const float* bp = (seg == 0) ? bb0 : ((seg == 1) ? bb1 : bb2);
    const int n0 = blockIdx.x * 256;
    const int tn = tid & 31, to = tid >> 5;

    float bias[8];
    #pragma unroll
    for (int j = 0; j < 8; j++) bias[j] = bp ? bp[to * 8 + j] : 0.f;
    float acc[8][8];
    #pragma unroll
    for (int i = 0; i < 8; i++)
        #pragma unroll
        for (int j = 0; j < 8; j++) acc[i][j] = bias[j];

    for (int kc = 0; kc < K; kc += 32) {
        // stage A^T tile: col = node-n0, row = k_local
        {
            const int nb = tid >> 3, k4 = (tid & 7) * 4;
            #pragma unroll
            for (int i = 0; i < 8; i++) {
                int col = nb + 32 * i;
                int n = n0 + col; if (n > NN - 1) n = NN - 1;
                float4 v = *(const float4*)&A[(long)n * K + kc + k4];
                int base = k4 * PADA + col;
                At[base] = v.x; At[base + PADA] = v.y;
                At[base + 2 * PADA] = v.z; At[base + 3 * PADA] = v.w;
            }
            const int oc = tid & 63, k8 = (tid >> 6) * 8;
            float4 w0 = *(const float4*)&W[(long)oc * K + kc + k8];
            float4 w1 = *(const float4*)&W[(long)oc * K + kc + k8 + 4];
            Bt[(k8 + 0) * PADBW + oc] = w0.x; Bt[(k8 + 1) * PADBW + oc] = w0.y;
            Bt[(k8 + 2) * PADBW + oc] = w0.z; Bt[(k8 + 3) * PADBW + oc] = w0.w;
            Bt[(k8 + 4) * PADBW + oc] = w1.x; Bt[(k8 + 5) * PADBW + oc] = w1.y;
            Bt[(k8 + 6) * PADBW + oc] = w1.z; Bt[(k8 + 7) * PADBW + oc] = w1.w;
        }
        __syncthreads();
        #pragma unroll 4
        for (int k = 0; k < 32; k++) {
            float4 a0 = *(const float4*)&At[k * PADA + tn * 4];
            float4 a1 = *(const float4*)&At[k * PADA + 128 + tn * 4];
            float4 b0 = *(const float4*)&Bt[k * PADBW + to * 8];
            float4 b1 = *(const float4*)&Bt[k * PADBW + to * 8 + 4];
            float av[8] = {a0.x, a0.y, a0.z, a0.w, a1.x, a1.y, a1.z, a1.w};
            float bv[8] = {b0.x, b0.y, b0.z, b0.w, b1.x, b1.y, b1.z, b1.w};
            #pragma unroll
            for (int i = 0; i < 8; i++)
                #pragma unroll
                for (int j = 0; j < 8; j++)
                    acc[i][j] = fmaf(av[i], bv[j], acc[i][j]);
        }
        __syncthreads();
    }
    // store
    #pragma unroll
    for (int i = 0; i < 8; i++) {
        int n = n0 + ((i < 4) ? (tn * 4 + i) : (128 + tn * 4 + i - 4));
        if (n < NN) {
            float* cp = &C[(long)n * Ntot + seg * 64 + to * 8];
            *(float4*)cp       = make_float4(acc[i][0], acc[i][1], acc[i][2], acc[i][3]);
            *(float4*)(cp + 4) = make_float4(acc[i][4], acc[i][5], acc[i][6], acc[i][7]);
        }
    }
}

// ---------------- gather (mean aggr) + self term + BN stats, fused ----------------
__global__ __launch_bounds__(256) void gather_bn_kernel(
    const int* __restrict__ off, const int* __restrict__ ebuf,
    const float* __restrict__ xlbase, int xst,
    float* __restrict__ vbase, int vst,
    float* __restrict__ bnsum, float* __restrict__ bnsq)
{
    __shared__ float r1[4][64], r2[4][64];
    const int lane = threadIdx.x & 63;
    const int wid = __builtin_amdgcn_readfirstlane(threadIdx.x >> 6);
    float s = 0.f, q = 0.f;
    for (int n = blockIdx.x * 4 + wid; n < NN; n += gridDim.x * 4) {
        const int a = off[n], b = off[n + 1];
        float acc = 0.f;
        for (int p = a; p < b; ++p) {
            int sidx = ebuf[p];
            acc += xlbase[(long)sidx * xst + lane];
        }
        float v = acc / fmaxf((float)(b - a), 1.f) + vbase[(long)n * vst + lane];
        vbase[(long)n * vst + lane] = v;
        s += v; q += v * v;
    }
    r1[wid][lane] = s; r2[wid][lane] = q;
    __syncthreads();
    if (threadIdx.x < 64) {
        s = r1[0][lane] + r1[1][lane] + r1[2][lane] + r1[3][lane];
        q = r2[0][lane] + r2[1][lane] + r2[2][lane] + r2[3][lane];
        atomicAdd(&bnsum[lane], s);
        atomicAdd(&bnsq[lane], q);
    }
}

// ---------------- BN finalize ----------------
__global__ void bnfin_kernel(const float* __restrict__ bnsum, const float* __restrict__ bnsq,
                             const float* __restrict__ g, const float* __restrict__ be,
                             float* __restrict__ scale, float* __restrict__ shift)
{
    int c = threadIdx.x;  // 64
    float inv_n = 1.0f / (float)NN;
    float mu = bnsum[c] * inv_n;
    float var = bnsq[c] * inv_n - mu * mu;
    float rstd = rsqrtf(var + EPSV);
    float sc = g[c] * rstd;
    scale[c] = sc;
    shift[c] = be[c] - mu * sc;
}

// ---------------- BN apply + ReLU + residual ----------------
__global__ void apply_kernel(const float* __restrict__ vbase, int vst,
                             const float* __restrict__ resbase, int rst,
                             const float* __restrict__ scale, const float* __restrict__ shift,
                             float* __restrict__ h, ushort* hb)
{
    const int stride = gridDim.x * 256;
    for (int i = blockIdx.x * 256 + threadIdx.x; i < NN * 16; i += stride) {
        int n = i >> 4;
        int c0 = (i & 15) * 4;
        float4 v = *(const float4*)&vbase[(long)n * vst + c0];
        float4 r = *(const float4*)&resbase[(long)n * rst + c0];
        float4 o;
        o.x = fmaxf(fmaf(v.x, scale[c0 + 0], shift[c0 + 0]), 0.f) + r.x;
        o.y = fmaxf(fmaf(v.y, scale[c0 + 1], shift[c0 + 1]), 0.f) + r.y;
        o.z = fmaxf(fmaf(v.z, scale[c0 + 2], shift[c0 + 2]), 0.f) + r.z;
        o.w = fmaxf(fmaf(v.w, scale[c0 + 3], shift[c0 + 3]), 0.f) + r.w;
        *(float4*)&h[(long)n * 64 + c0] = o;
        if (hb) {
            union { ushort u[4]; uint2 v2; } p;
            p.u[0] = f2b(o.x); p.u[1] = f2b(o.y); p.u[2] = f2b(o.z); p.u[3] = f2b(o.w);
            *(uint2*)&hb[(long)n * 64 + c0] = p.v2;
        }
    }
}

// ---------------- fused edge MLP, bf16 MFMA (unchanged from R1) ----------------
#define TILE 128
#define PADB 136

__global__ __launch_bounds__(512, 2) void edge_mlp_mfma_kernel(
    const ushort* __restrict__ hb,
    const int* __restrict__ src, const int* __restrict__ tgt,
    const ushort* __restrict__ W1b, const ushort* __restrict__ W2b,
    const float* __restrict__ b1, const float* __restrict__ b2,
    const float* __restrict__ W3, const float* __restrict__ b3,
    float* __restrict__ out)
{
    __shared__ ushort inb[TILE * PADB];
    __shared__ ushort zb [TILE * PADB];
    __shared__ float red[2][TILE];

    const int tid = threadIdx.x;
    const int wid = tid >> 6, lane = tid & 63;
    const int l15 = lane & 15, l4 = lane >> 4;
    const int es = wid & 3, os = wid >> 2;
    const int m0 = es * 32;
    const int ocb = os * 64;

    bf16x8 w1f[4][4], w2f[4][4];
    #pragma unroll
    for (int n = 0; n < 4; n++) {
        const int oc = ocb + n * 16 + l15;
        #pragma unroll
        for (int ks = 0; ks < 4; ks++) {
            const int k = ks * 32 + l4 * 8;
            w1f[n][ks] = *(const bf16x8*)&W1b[oc * 128 + k];
            w2f[n][ks] = *(const bf16x8*)&W2b[oc * 128 + k];
        }
    }
    float b1v[4], b2v[4], w3v[4];
    #pragma unroll
    for (int n = 0; n < 4; n++) {
        b1v[n] = b1[ocb + n * 16 + l15];
        b2v[n] = b2[ocb + n * 16 + l15];
        w3v[n] = W3[ocb + n * 16 + l15];
    }
    const float b3v = b3[0];

    for (int t = blockIdx.x; t < NE / TILE; t += gridDim.x) {
        const int e0 = t * TILE;
        for (int i = tid; i < TILE * 16; i += 512) {
            int e = i >> 4, q = i & 15;
            int node = (q < 8) ? src[e0 + e] : tgt[e0 + e];
            int c8 = (q & 7) * 8;
            int4v v = *(const int4v*)&hb[node * 64 + c8];
            *(int4v*)&inb[e * PADB + ((q & 8) << 3) + c8] = v;
        }
        __syncthreads();

        f32x4 acc1[2][4];
        #pragma unroll
        for (int ms = 0; ms < 2; ms++)
            #pragma unroll
            for (int n = 0; n < 4; n++)
                acc1[ms][n] = (f32x4){b1v[n], b1v[n], b1v[n], b1v[n]};
        #pragma unroll
        for (int ms = 0; ms < 2; ms++) {
            const int erow = m0 + ms * 16 + l15;
            #pragma unroll
            for (int ks = 0; ks < 4; ks++) {
                bf16x8 a = *(const bf16x8*)&inb[erow * PADB + ks * 32 + l4 * 8];
                #pragma unroll
                for (int n = 0; n < 4; n++)
                    acc1[ms][n] = __builtin_amdgcn_mfma_f32_16x16x32_bf16(a, w1f[n][ks], acc1[ms][n], 0, 0, 0);
            }
        }
        #pragma unroll
        for (int ms = 0; ms < 2; ms++)
            #pragma unroll
            for (int n = 0; n < 4; n++) {
                const int ebase = m0 + ms * 16 + l4 * 4;
                const int oc = ocb + n * 16 + l15;
                #pragma unroll
                for (int r = 0; r < 4; r++)
                    zb[(ebase + r) * PADB + oc] = f2b(fmaxf(acc1[ms][n][r], 0.f));
            }
        __syncthreads();

        f32x4 acc2[2][4];
        #pragma unroll
        for (int ms = 0; ms < 2; ms++)
            #pragma unroll
            for (int n = 0; n < 4; n++)
                acc2[ms][n] = (f32x4){b2v[n], b2v[n], b2v[n], b2v[n]};
        #pragma unroll
        for (int ms = 0; ms < 2; ms++) {
            const int erow = m0 + ms * 16 + l15;
            #pragma unroll
            for (int ks = 0; ks < 4; ks++) {
                bf16x8 a = *(const bf16x8*)&zb[erow * PADB + ks * 32 + l4 * 8];
                #pragma unroll
                for (int n = 0; n < 4; n++)
                    acc2[ms][n] = __builtin_amdgcn_mfma_f32_16x16x32_bf16(a, w2f[n][ks], acc2[ms][n], 0, 0, 0);
            }
        }

        #pragma unroll
        for (int ms = 0; ms < 2; ms++) {
            #pragma unroll
            for (int r = 0; r < 4; r++) {
                float p = 0.f;
                #pragma unroll
                for (int n = 0; n < 4; n++)
                    p = fmaf(fmaxf(acc2[ms][n][r], 0.f), w3v[n], p);
                p += __shfl_xor(p, 1);
                p += __shfl_xor(p, 2);
                p += __shfl_xor(p, 4);
                p += __shfl_xor(p, 8);
                if (l15 == 0) red[os][m0 + ms * 16 + l4 * 4 + r] = p;
            }
        }
        __syncthreads();
        if (tid < TILE) out[e0 + tid] = red[0][tid] + red[1][tid] + b3v;
        __syncthreads();
    }
}

// ---------------- launch ----------------
extern "C" void kernel_launch(void* const* d_in, const int* in_sizes, int n_in,
                              void* d_out, int out_size, void* d_ws, size_t ws_size,
                              hipStream_t stream)
{
    const float* x   = (const float*)d_in[0];
    const int*   ei  = (const int*)d_in[1];
    const int* src = ei;
    const int* tgt = ei + NE;
    const float* Wl0 = (const float*)d_in[2];
    const float* bl0 = (const float*)d_in[3];
    const float* Wr0 = (const float*)d_in[4];
    const float* g0  = (const float*)d_in[5];
    const float* be0 = (const float*)d_in[6];
    const float* rW0 = (const float*)d_in[7];
    const float* rb0 = (const float*)d_in[8];
    const float* Wl1 = (const float*)d_in[9];
    const float* bl1 = (const float*)d_in[10];
    const float* Wr1 = (const float*)d_in[11];
    const float* g1  = (const float*)d_in[12];
    const float* be1 = (const float*)d_in[13];
    const float* Wl2 = (const float*)d_in[14];
    const float* bl2 = (const float*)d_in[15];
    const float* Wr2 = (const float*)d_in[16];
    const float* g2  = (const float*)d_in[17];
    const float* be2 = (const float*)d_in[18];
    const float* W1  = (const float*)d_in[19];
    const float* b1  = (const float*)d_in[20];
    const float* W2  = (const float*)d_in[21];
    const float* b2  = (const float*)d_in[22];
    const float* W3  = (const float*)d_in[23];
    const float* b3  = (const float*)d_in[24];
    float* out = (float*)d_out;

    float* ws = (float*)d_ws;
    float*  xlpr = ws;                           // 50000*192 = 9.6M
    float*  hbuf = ws + 9600000;                 // 3.2M
    float*  bn   = ws + 12800000;                // 256
    float*  bnsum = bn, *bnsq = bn + 64, *bnsc = bn + 128, *bnsh = bn + 192;
    ushort* hb   = (ushort*)(ws + 12800256);     // 3.2M ushort
    ushort* W1b  = (ushort*)(ws + 14400256);     // 16384
    ushort* W2b  = W1b + 16384;                  // 16384
    int*    icnt = (int*)(ws + 14416640);        // 50000
    int*    off  = icnt + 50000;                 // 50001
    int*    woff = off + 50001;                  // 50000
    int*    ebuf = woff + 50000;                 // 800000
    int*    bsum = ebuf + 800000;                // 256
    int*    bpre = bsum + 256;                   // 256

    // ---- one-time prep: bf16 weights + CSR ----
    prep_w_kernel<<<128, 256, 0, stream>>>(W1, W2, W1b, W2b);
    hipMemsetAsync(icnt, 0, NN * sizeof(int), stream);
    count_kernel<<<NE / 256, 256, 0, stream>>>(tgt, icnt);
    scan1_kernel<<<NBLK, 256, 0, stream>>>(icnt, off, bsum);
    scan2_kernel<<<1, 256, 0, stream>>>(bsum, bpre);
    scan3_kernel<<<NBLK, 256, 0, stream>>>(icnt, bpre, off, woff);
    fill_kernel<<<NE / 256, 256, 0, stream>>>(src, tgt, woff, ebuf);

    dim3 g0g(196, 3), g12g(196, 2);

    // ---- layer 0 ----
    hipMemsetAsync(bnsum, 0, 128 * sizeof(float), stream);
    proj_gemm_kernel<<<g0g, 256, 0, stream>>>(x, 128, Wl0, Wr0, rW0,
                                              nullptr, bl0, rb0, xlpr, 192);
    gather_bn_kernel<<<512, 256, 0, stream>>>(off, ebuf, xlpr, 192,
                                              xlpr + 64, 192, bnsum, bnsq);
    bnfin_kernel<<<1, 64, 0, stream>>>(bnsum, bnsq, g0, be0, bnsc, bnsh);
    apply_kernel<<<1024, 256, 0, stream>>>(xlpr + 64, 192, xlpr + 128, 192,
                                           bnsc, bnsh, hbuf, nullptr);

    // ---- layer 1 ----
    hipMemsetAsync(bnsum, 0, 128 * sizeof(float), stream);
    proj_gemm_kernel<<<g12g, 256, 0, stream>>>(hbuf, 64, Wl1, Wr1, nullptr,
                                               nullptr, bl1, nullptr, xlpr, 128);
    gather_bn_kernel<<<512, 256, 0, stream>>>(off, ebuf, xlpr, 128,
                                              xlpr + 64, 128, bnsum, bnsq);
    bnfin_kernel<<<1, 64, 0, stream>>>(bnsum, bnsq, g1, be1, bnsc, bnsh);
    apply_kernel<<<1024, 256, 0, stream>>>(xlpr + 64, 128, hbuf, 64,
                                           bnsc, bnsh, hbuf, nullptr);

    // ---- layer 2 ----
    hipMemsetAsync(bnsum, 0, 128 * sizeof(float), stream);
    proj_gemm_kernel<<<g12g, 256, 0, stream>>>(hbuf, 64, Wl2, Wr2, nullptr,
                                               nullptr, bl2, nullptr, xlpr, 128);
    gather_bn_kernel<<<512, 256, 0, stream>>>(off, ebuf, xlpr, 128,
                                              xlpr + 64, 128, bnsum, bnsq);
    bnfin_kernel<<<1, 64, 0, stream>>>(bnsum, bnsq, g2, be2, bnsc, bnsh);
    apply_kernel<<<1024, 256, 0, stream>>>(xlpr + 64, 128, hbuf, 64,
                                           bnsc, bnsh, hbuf, hb);

    // ---- edge MLP (bf16 MFMA) ----
    edge_mlp_mfma_kernel<<<625, 512, 0, stream>>>(hb, src, tgt, W1b, W2b, b1, b2, W3, b3, out);
}

// Round 5
// 583.961 us; speedup vs baseline: 3.6070x; 1.3810x over previous
//
#include <hip/hip_runtime.h>
#include <hip/hip_bf16.h>

#define NN 50000
#define NE 800000
#define HID 64
#define EPSV 1e-5f
#define NBLK 196            // ceil(NN/256)

typedef __attribute__((ext_vector_type(8))) short bf16x8;
typedef __attribute__((ext_vector_type(4))) float f32x4;
typedef __attribute__((ext_vector_type(4))) int int4v;

__device__ __forceinline__ ushort f2b(float f) {
    union { __hip_bfloat16 b; ushort u; } c;
    c.b = __float2bfloat16(f);
    return c.u;
}
__device__ __forceinline__ float b2f(ushort u) {
    return __uint_as_float(((unsigned int)u) << 16);
}

// ---------------- weight f32 -> bf16 prep (edge MLP) ----------------
__global__ void prep_w_kernel(const float* __restrict__ W1, const float* __restrict__ W2,
                              ushort* __restrict__ W1b, ushort* __restrict__ W2b) {
    int i = blockIdx.x * 256 + threadIdx.x;   // 0..32767
    if (i < 16384) W1b[i] = f2b(W1[i]);
    else           W2b[i - 16384] = f2b(W2[i - 16384]);
}

// ---------------- CSR build: count, scan, fill ----------------
__global__ void count_kernel(const int* __restrict__ tgt, int* __restrict__ icnt) {
    int e = blockIdx.x * 256 + threadIdx.x;
    if (e < NE) atomicAdd(&icnt[tgt[e]], 1);
}

__global__ void scan1_kernel(const int* __restrict__ icnt, int* __restrict__ off,
                             int* __restrict__ bsum) {
    __shared__ int s[256];
    const int t = threadIdx.x;
    const int i = blockIdx.x * 256 + t;
    int v = (i < NN) ? icnt[i] : 0;
    s[t] = v;
    __syncthreads();
    for (int d = 1; d < 256; d <<= 1) {
        int x = (t >= d) ? s[t - d] : 0;
        __syncthreads();
        s[t] += x;
        __syncthreads();
    }
    if (i < NN) off[i] = s[t];             // inclusive, block-local
    if (t == 255) bsum[blockIdx.x] = s[255];
}

__global__ void scan2_kernel(const int* __restrict__ bsum, int* __restrict__ bpre) {
    __shared__ int s[256];
    const int t = threadIdx.x;
    int v = (t < NBLK) ? bsum[t] : 0;
    s[t] = v;
    __syncthreads();
    for (int d = 1; d < 256; d <<= 1) {
        int x = (t >= d) ? s[t - d] : 0;
        __syncthreads();
        s[t] += x;
        __syncthreads();
    }
    if (t < NBLK) bpre[t] = s[t] - v;      // exclusive
}

__global__ void scan3_kernel(const int* __restrict__ icnt, const int* __restrict__ bpre,
                             int* __restrict__ off, int* __restrict__ woff) {
    const int i = blockIdx.x * 256 + threadIdx.x;
    if (i < NN) {
        int e = off[i] - icnt[i] + bpre[blockIdx.x];   // exclusive global
        off[i] = e;
        woff[i] = e;
        if (i == NN - 1) off[NN] = NE;
    }
}

__global__ void fill_kernel(const int* __restrict__ src, const int* __restrict__ tgt,
                            int* __restrict__ woff, int* __restrict__ ebuf) {
    int e = blockIdx.x * 256 + threadIdx.x;
    if (e < NE) {
        int p = atomicAdd(&woff[tgt[e]], 1);
        ebuf[p] = src[e];
    }
}

// ---------------- projection GEMM ----------------
// seg0: xb (bf16) = A @ W0.T        seg1: pre = A @ W1s.T + bias1
// seg2: res = A @ W2s.T + bias2 (layer 0 only)
#define PADA 260
#define PADBW 68

__global__ __launch_bounds__(256, 2) void proj_gemm_kernel(
    const float* __restrict__ A, int K,
    const float* __restrict__ W0, const float* __restrict__ W1s,
    const float* __restrict__ W2s,
    const float* __restrict__ bias1, const float* __restrict__ bias2,
    ushort* __restrict__ xb, float* __restrict__ pre, float* __restrict__ res)
{
    __shared__ float At[32 * PADA];
    __shared__ float Bt[32 * PADBW];
    const int tid = threadIdx.x;
    const int seg = blockIdx.y;
    const float* W  = (seg == 0) ? W0 : ((seg == 1) ? W1s : W2s);
    const float* bp = (seg == 1) ? bias1 : ((seg == 2) ? bias2 : nullptr);
    const int n0 = blockIdx.x * 256;
    const int tn = tid & 31, to = tid >> 5;

    float bias[8];
    #pragma unroll
    for (int j = 0; j < 8; j++) bias[j] = bp ? bp[to * 8 + j] : 0.f;
    float acc[8][8];
    #pragma unroll
    for (int i = 0; i < 8; i++)
        #pragma unroll
        for (int j = 0; j < 8; j++) acc[i][j] = bias[j];

    for (int kc = 0; kc < K; kc += 32) {
        {
            const int nb = tid >> 3, k4 = (tid & 7) * 4;
            #pragma unroll
            for (int i = 0; i < 8; i++) {
                int col = nb + 32 * i;
                int n = n0 + col; if (n > NN - 1) n = NN - 1;
                float4 v = *(const float4*)&A[(long)n * K + kc + k4];
                int base = k4 * PADA + col;
                At[base] = v.x; At[base + PADA] = v.y;
                At[base + 2 * PADA] = v.z; At[base + 3 * PADA] = v.w;
            }
            const int oc = tid & 63, k8 = (tid >> 6) * 8;
            float4 w0 = *(const float4*)&W[(long)oc * K + kc + k8];
            float4 w1 = *(const float4*)&W[(long)oc * K + kc + k8 + 4];
            Bt[(k8 + 0) * PADBW + oc] = w0.x; Bt[(k8 + 1) * PADBW + oc] = w0.y;
            Bt[(k8 + 2) * PADBW + oc] = w0.z; Bt[(k8 + 3) * PADBW + oc] = w0.w;
            Bt[(k8 + 4) * PADBW + oc] = w1.x; Bt[(k8 + 5) * PADBW + oc] = w1.y;
            Bt[(k8 + 6) * PADBW + oc] = w1.z; Bt[(k8 + 7) * PADBW + oc] = w1.w;
        }
        __syncthreads();
        #pragma unroll 4
        for (int k = 0; k < 32; k++) {
            float4 a0 = *(const float4*)&At[k * PADA + tn * 4];
            float4 a1 = *(const float4*)&At[k * PADA + 128 + tn * 4];
            float4 b0 = *(const float4*)&Bt[k * PADBW + to * 8];
            float4 b1 = *(const float4*)&Bt[k * PADBW + to * 8 + 4];
            float av[8] = {a0.x, a0.y, a0.z, a0.w, a1.x, a1.y, a1.z, a1.w};
            float bv[8] = {b0.x, b0.y, b0.z, b0.w, b1.x, b1.y, b1.z, b1.w};
            #pragma unroll
            for (int i = 0; i < 8; i++)
                #pragma unroll
                for (int j = 0; j < 8; j++)
                    acc[i][j] = fmaf(av[i], bv[j], acc[i][j]);
        }
        __syncthreads();
    }
    #pragma unroll
    for (int i = 0; i < 8; i++) {
        int n = n0 + ((i < 4) ? (tn * 4 + i) : (128 + tn * 4 + i - 4));
        if (n < NN) {
            if (seg == 0) {
                union { ushort u[8]; int4v v; } pk;
                #pragma unroll
                for (int j = 0; j < 8; j++) pk.u[j] = f2b(acc[i][j]);
                *(int4v*)&xb[(long)n * 64 + to * 8] = pk.v;
            } else {
                float* O = (seg == 1) ? pre : res;
                float* cp = &O[(long)n * 64 + to * 8];
                *(float4*)cp       = make_float4(acc[i][0], acc[i][1], acc[i][2], acc[i][3]);
                *(float4*)(cp + 4) = make_float4(acc[i][4], acc[i][5], acc[i][6], acc[i][7]);
            }
        }
    }
}

// ---------------- gather (mean aggr, bf16 src) + self term + BN stats ----------------
__global__ __launch_bounds__(256) void gather_bn_kernel(
    const int* __restrict__ off, const int* __restrict__ ebuf,
    const ushort* __restrict__ xb,
    float* __restrict__ vbase,
    float* __restrict__ bnsum, float* __restrict__ bnsq)
{
    __shared__ float r1[4][64], r2[4][64];
    const int lane = threadIdx.x & 63;
    const int wid = __builtin_amdgcn_readfirstlane(threadIdx.x >> 6);
    float s = 0.f, q = 0.f;
    for (int n = blockIdx.x * 4 + wid; n < NN; n += gridDim.x * 4) {
        const int a = off[n], b = off[n + 1];
        float a0 = 0.f, a1 = 0.f, a2 = 0.f, a3 = 0.f;
        int p = a;
        for (; p + 4 <= b; p += 4) {
            int s0 = ebuf[p], s1 = ebuf[p + 1], s2 = ebuf[p + 2], s3 = ebuf[p + 3];
            a0 += b2f(xb[(long)s0 * 64 + lane]);
            a1 += b2f(xb[(long)s1 * 64 + lane]);
            a2 += b2f(xb[(long)s2 * 64 + lane]);
            a3 += b2f(xb[(long)s3 * 64 + lane]);
        }
        for (; p < b; ++p) a0 += b2f(xb[(long)ebuf[p] * 64 + lane]);
        float acc = (a0 + a1) + (a2 + a3);
        float v = acc / fmaxf((float)(b - a), 1.f) + vbase[(long)n * 64 + lane];
        vbase[(long)n * 64 + lane] = v;
        s += v; q += v * v;
    }
    r1[wid][lane] = s; r2[wid][lane] = q;
    __syncthreads();
    if (threadIdx.x < 64) {
        s = r1[0][lane] + r1[1][lane] + r1[2][lane] + r1[3][lane];
        q = r2[0][lane] + r2[1][lane] + r2[2][lane] + r2[3][lane];
        atomicAdd(&bnsum[lane], s);
        atomicAdd(&bnsq[lane], q);
    }
}

// ---------------- BN finalize ----------------
__global__ void bnfin_kernel(const float* __restrict__ bnsum, const float* __restrict__ bnsq,
                             const float* __restrict__ g, const float* __restrict__ be,
                             float* __restrict__ scale, float* __restrict__ shift)
{
    int c = threadIdx.x;  // 64
    float inv_n = 1.0f / (float)NN;
    float mu = bnsum[c] * inv_n;
    float var = bnsq[c] * inv_n - mu * mu;
    float rstd = rsqrtf(var + EPSV);
    float sc = g[c] * rstd;
    scale[c] = sc;
    shift[c] = be[c] - mu * sc;
}

// ---------------- BN apply + ReLU + residual ----------------
__global__ void apply_kernel(const float* __restrict__ vbase,
                             const float* __restrict__ resbase,
                             const float* __restrict__ scale, const float* __restrict__ shift,
                             float* __restrict__ h, ushort* hb)
{
    const int stride = gridDim.x * 256;
    for (int i = blockIdx.x * 256 + threadIdx.x; i < NN * 16; i += stride) {
        int n = i >> 4;
        int c0 = (i & 15) * 4;
        float4 v = *(const float4*)&vbase[(long)n * 64 + c0];
        float4 r = *(const float4*)&resbase[(long)n * 64 + c0];
        float4 o;
        o.x = fmaxf(fmaf(v.x, scale[c0 + 0], shift[c0 + 0]), 0.f) + r.x;
        o.y = fmaxf(fmaf(v.y, scale[c0 + 1], shift[c0 + 1]), 0.f) + r.y;
        o.z = fmaxf(fmaf(v.z, scale[c0 + 2], shift[c0 + 2]), 0.f) + r.z;
        o.w = fmaxf(fmaf(v.w, scale[c0 + 3], shift[c0 + 3]), 0.f) + r.w;
        *(float4*)&h[(long)n * 64 + c0] = o;
        if (hb) {
            union { ushort u[4]; uint2 v2; } p;
            p.u[0] = f2b(o.x); p.u[1] = f2b(o.y); p.u[2] = f2b(o.z); p.u[3] = f2b(o.w);
            *(uint2*)&hb[(long)n * 64 + c0] = p.v2;
        }
    }
}

// ---------------- fused edge MLP, bf16 MFMA ----------------
// 512 threads = 8 waves: es = wid&3 (32 edges each), os = wid>>2 (64 ocs each).
// Z1 aliases inb (single LDS tile) -> 35.8 KB. Staging split: gathers issued
// to regs at loop top, ds_write later; weight-frag loads overlap idx chain.
#define TILE 128
#define PADB 136
#define EMGRID 3125

__global__ __launch_bounds__(512, 2) void edge_mlp_mfma_kernel(
    const ushort* __restrict__ hb,
    const int* __restrict__ src, const int* __restrict__ tgt,
    const ushort* __restrict__ W1b, const ushort* __restrict__ W2b,
    const float* __restrict__ b1, const float* __restrict__ b2,
    const float* __restrict__ W3, const float* __restrict__ b3,
    float* __restrict__ out)
{
    __shared__ ushort inb[TILE * PADB];   // input tile, then Z1 tile (aliased)
    __shared__ float red[2][TILE];

    const int tid = threadIdx.x;
    const int wid = tid >> 6, lane = tid & 63;
    const int l15 = lane & 15, l4 = lane >> 4;
    const int es = wid & 3, os = wid >> 2;
    const int m0 = es * 32;
    const int ocb = os * 64;

    // persistent weight fragments: lane holds oc=l15, k=ks*32+l4*8+j
    bf16x8 w1f[4][4], w2f[4][4];
    #pragma unroll
    for (int n = 0; n < 4; n++) {
        const int oc = ocb + n * 16 + l15;
        #pragma unroll
        for (int ks = 0; ks < 4; ks++) {
            const int k = ks * 32 + l4 * 8;
            w1f[n][ks] = *(const bf16x8*)&W1b[oc * 128 + k];
            w2f[n][ks] = *(const bf16x8*)&W2b[oc * 128 + k];
        }
    }
    float b1v[4], b2v[4], w3v[4];
    #pragma unroll
    for (int n = 0; n < 4; n++) {
        b1v[n] = b1[ocb + n * 16 + l15];
        b2v[n] = b2[ocb + n * 16 + l15];
        w3v[n] = W3[ocb + n * 16 + l15];
    }
    const float b3v = b3[0];

    for (int t = blockIdx.x; t < NE / TILE; t += EMGRID) {
        const int e0 = t * TILE;

        // ---- issue gathers into registers (idx then data; independent across r) ----
        int idx[4];
        #pragma unroll
        for (int r = 0; r < 4; r++) {
            int i = tid + r * 512;
            int e = i >> 4, q = i & 15;
            idx[r] = (q < 8) ? src[e0 + e] : tgt[e0 + e];
        }
        int4v gv[4];
        #pragma unroll
        for (int r = 0; r < 4; r++) {
            int i = tid + r * 512;
            int q = i & 15, c8 = (q & 7) * 8;
            gv[r] = *(const int4v*)&hb[(long)idx[r] * 64 + c8];
        }
        // ---- write staged tile ----
        #pragma unroll
        for (int r = 0; r < 4; r++) {
            int i = tid + r * 512;
            int e = i >> 4, q = i & 15, c8 = (q & 7) * 8;
            *(int4v*)&inb[e * PADB + ((q & 8) << 3) + c8] = gv[r];
        }
        __syncthreads();   // B1: inb ready

        // ---- layer 1: Z1 = relu(IN @ W1.T + b1) ----
        f32x4 acc1[2][4];
        #pragma unroll
        for (int ms = 0; ms < 2; ms++)
            #pragma unroll
            for (int n = 0; n < 4; n++)
                acc1[ms][n] = (f32x4){b1v[n], b1v[n], b1v[n], b1v[n]};
        #pragma unroll
        for (int ms = 0; ms < 2; ms++) {
            const int erow = m0 + ms * 16 + l15;
            #pragma unroll
            for (int ks = 0; ks < 4; ks++) {
                bf16x8 a = *(const bf16x8*)&inb[erow * PADB + ks * 32 + l4 * 8];
                #pragma unroll
                for (int n = 0; n < 4; n++)
                    acc1[ms][n] = __builtin_amdgcn_mfma_f32_16x16x32_bf16(a, w1f[n][ks], acc1[ms][n], 0, 0, 0);
            }
        }
        __syncthreads();   // B2: inb fully consumed, safe to overwrite with Z1

        #pragma unroll
        for (int ms = 0; ms < 2; ms++)
            #pragma unroll
            for (int n = 0; n < 4; n++) {
                const int ebase = m0 + ms * 16 + l4 * 4;
                const int oc = ocb + n * 16 + l15;
                #pragma unroll
                for (int r = 0; r < 4; r++)
                    inb[(ebase + r) * PADB + oc] = f2b(fmaxf(acc1[ms][n][r], 0.f));
            }
        __syncthreads();   // B3: Z1 ready

        // ---- layer 2: Z2 = relu(Z1 @ W2.T + b2), kept in regs ----
        f32x4 acc2[2][4];
        #pragma unroll
        for (int ms = 0; ms < 2; ms++)
            #pragma unroll
            for (int n = 0; n < 4; n++)
                acc2[ms][n] = (f32x4){b2v[n], b2v[n], b2v[n], b2v[n]};
        #pragma unroll
        for (int ms = 0; ms < 2; ms++) {
            const int erow = m0 + ms * 16 + l15;
            #pragma unroll
            for (int ks = 0; ks < 4; ks++) {
                bf16x8 a = *(const bf16x8*)&inb[erow * PADB + ks * 32 + l4 * 8];
                #pragma unroll
                for (int n = 0; n < 4; n++)
                    acc2[ms][n] = __builtin_amdgcn_mfma_f32_16x16x32_bf16(a, w2f[n][ks], acc2[ms][n], 0, 0, 0);
            }
        }

        // ---- layer 3: out = relu(Z2) @ W3.T + b3 ----
        #pragma unroll
        for (int ms = 0; ms < 2; ms++) {
            #pragma unroll
            for (int r = 0; r < 4; r++) {
                float p = 0.f;
                #pragma unroll
                for (int n = 0; n < 4; n++)
                    p = fmaf(fmaxf(acc2[ms][n][r], 0.f), w3v[n], p);
                p += __shfl_xor(p, 1);
                p += __shfl_xor(p, 2);
                p += __shfl_xor(p, 4);
                p += __shfl_xor(p, 8);
                if (l15 == 0) red[os][m0 + ms * 16 + l4 * 4 + r] = p;
            }
        }
        __syncthreads();   // B4: red ready; inb consumed for next iter
        if (tid < TILE) out[e0 + tid] = red[0][tid] + red[1][tid] + b3v;
    }
}

// ---------------- launch ----------------
extern "C" void kernel_launch(void* const* d_in, const int* in_sizes, int n_in,
                              void* d_out, int out_size, void* d_ws, size_t ws_size,
                              hipStream_t stream)
{
    const float* x   = (const float*)d_in[0];
    const int*   ei  = (const int*)d_in[1];
    const int* src = ei;
    const int* tgt = ei + NE;
    const float* Wl0 = (const float*)d_in[2];
    const float* bl0 = (const float*)d_in[3];
    const float* Wr0 = (const float*)d_in[4];
    const float* g0  = (const float*)d_in[5];
    const float* be0 = (const float*)d_in[6];
    const float* rW0 = (const float*)d_in[7];
    const float* rb0 = (const float*)d_in[8];
    const float* Wl1 = (const float*)d_in[9];
    const float* bl1 = (const float*)d_in[10];
    const float* Wr1 = (const float*)d_in[11];
    const float* g1  = (const float*)d_in[12];
    const float* be1 = (const float*)d_in[13];
    const float* Wl2 = (const float*)d_in[14];
    const float* bl2 = (const float*)d_in[15];
    const float* Wr2 = (const float*)d_in[16];
    const float* g2  = (const float*)d_in[17];
    const float* be2 = (const float*)d_in[18];
    const float* W1  = (const float*)d_in[19];
    const float* b1  = (const float*)d_in[20];
    const float* W2  = (const float*)d_in[21];
    const float* b2  = (const float*)d_in[22];
    const float* W3  = (const float*)d_in[23];
    const float* b3  = (const float*)d_in[24];
    float* out = (float*)d_out;

    float* ws = (float*)d_ws;
    float*  pre  = ws;                           // [0, 3.2M)
    float*  res  = ws + 3200000;                 // [3.2M, 6.4M)
    float*  hbuf = ws + 6400000;                 // [6.4M, 9.6M)
    float*  bn   = ws + 9600000;                 // 256
    float*  bnsum = bn, *bnsq = bn + 64, *bnsc = bn + 128, *bnsh = bn + 192;
    ushort* xb   = (ushort*)(ws + 9600256);      // 3.2M ushort -> floats [9600256, 11200256)
    ushort* hb   = (ushort*)(ws + 11200256);     // 3.2M ushort -> floats [11200256, 12800256)
    ushort* W1b  = (ushort*)(ws + 12800256);     // 16384 ushort -> floats [12800256, 12808448)
    ushort* W2b  = W1b + 16384;                  // 16384 ushort -> floats [12808448, 12816640)
    int*    icnt = (int*)(ws + 12816640);        // 50000  (FIX: was 12808448, overlapped W2b)
    int*    off  = icnt + 50000;                 // 50001
    int*    woff = off + 50001;                  // 50000
    int*    ebuf = woff + 50000;                 // 800000
    int*    bsum = ebuf + 800000;                // 256
    int*    bpre = bsum + 256;                   // 256

    // ---- one-time prep: bf16 weights + CSR ----
    prep_w_kernel<<<128, 256, 0, stream>>>(W1, W2, W1b, W2b);
    hipMemsetAsync(icnt, 0, NN * sizeof(int), stream);
    count_kernel<<<NE / 256, 256, 0, stream>>>(tgt, icnt);
    scan1_kernel<<<NBLK, 256, 0, stream>>>(icnt, off, bsum);
    scan2_kernel<<<1, 256, 0, stream>>>(bsum, bpre);
    scan3_kernel<<<NBLK, 256, 0, stream>>>(icnt, bpre, off, woff);
    fill_kernel<<<NE / 256, 256, 0, stream>>>(src, tgt, woff, ebuf);

    dim3 g0g(NBLK, 3), g12g(NBLK, 2);

    // ---- layer 0 ----
    hipMemsetAsync(bnsum, 0, 128 * sizeof(float), stream);
    proj_gemm_kernel<<<g0g, 256, 0, stream>>>(x, 128, Wl0, Wr0, rW0,
                                              bl0, rb0, xb, pre, res);
    gather_bn_kernel<<<1024, 256, 0, stream>>>(off, ebuf, xb, pre, bnsum, bnsq);
    bnfin_kernel<<<1, 64, 0, stream>>>(bnsum, bnsq, g0, be0, bnsc, bnsh);
    apply_kernel<<<1024, 256, 0, stream>>>(pre, res, bnsc, bnsh, hbuf, nullptr);

    // ---- layer 1 ----
    hipMemsetAsync(bnsum, 0, 128 * sizeof(float), stream);
    proj_gemm_kernel<<<g12g, 256, 0, stream>>>(hbuf, 64, Wl1, Wr1, nullptr,
                                               bl1, nullptr, xb, pre, res);
    gather_bn_kernel<<<1024, 256, 0, stream>>>(off, ebuf, xb, pre, bnsum, bnsq);
    bnfin_kernel<<<1, 64, 0, stream>>>(bnsum, bnsq, g1, be1, bnsc, bnsh);
    apply_kernel<<<1024, 256, 0, stream>>>(pre, hbuf, bnsc, bnsh, hbuf, nullptr);

    // ---- layer 2 ----
    hipMemsetAsync(bnsum, 0, 128 * sizeof(float), stream);
    proj_gemm_kernel<<<g12g, 256, 0, stream>>>(hbuf, 64, Wl2, Wr2, nullptr,
                                               bl2, nullptr, xb, pre, res);
    gather_bn_kernel<<<1024, 256, 0, stream>>>(off, ebuf, xb, pre, bnsum, bnsq);
    bnfin_kernel<<<1, 64, 0, stream>>>(bnsum, bnsq, g2, be2, bnsc, bnsh);
    apply_kernel<<<1024, 256, 0, stream>>>(pre, hbuf, bnsc, bnsh, hbuf, hb);

    // ---- edge MLP (bf16 MFMA) ----
    edge_mlp_mfma_kernel<<<EMGRID, 512, 0, stream>>>(hb, src, tgt, W1b, W2b, b1, b2, W3, b3, out);
}